// Round 1
// baseline (210.693 us; speedup 1.0000x reference)
//
#include <hip/hip_runtime.h>

typedef unsigned short u16;
typedef short bf16x8 __attribute__((ext_vector_type(8)));
typedef float f32x4 __attribute__((ext_vector_type(4)));

#define NROWS 16384
#define DIM 128

// round-to-nearest-even f32 -> bf16 (inputs are finite)
__device__ __forceinline__ u16 f2bf(float f) {
    unsigned int u = __float_as_uint(f);
    u += 0x7fffu + ((u >> 16) & 1u);
    return (u16)(u >> 16);
}

// One wave per row: L2-normalize rows of a and b, emit bf16.
__global__ __launch_bounds__(256) void norm_kernel(
    const float* __restrict__ a, const float* __restrict__ b,
    u16* __restrict__ aO, u16* __restrict__ bO)
{
    int tid  = threadIdx.x;
    int lane = tid & 63;
    int w    = tid >> 6;
    long row = (long)blockIdx.x * 4 + w;

    const float2 va = ((const float2*)(a + row * DIM))[lane];
    float sa = va.x * va.x + va.y * va.y;
    #pragma unroll
    for (int off = 32; off; off >>= 1) sa += __shfl_xor(sa, off, 64);
    float inva = 1.0f / fmaxf(sqrtf(sa), 1e-12f);
    unsigned int pa = (unsigned int)f2bf(va.x * inva) | ((unsigned int)f2bf(va.y * inva) << 16);
    ((unsigned int*)(aO + row * DIM))[lane] = pa;

    const float2 vb = ((const float2*)(b + row * DIM))[lane];
    float sb = vb.x * vb.x + vb.y * vb.y;
    #pragma unroll
    for (int off = 32; off; off >>= 1) sb += __shfl_xor(sb, off, 64);
    float invb = 1.0f / fmaxf(sqrtf(sb), 1e-12f);
    unsigned int pb = (unsigned int)f2bf(vb.x * invb) | ((unsigned int)f2bf(vb.y * invb) << 16);
    ((unsigned int*)(bO + row * DIM))[lane] = pb;
}

// 128x128 C-tile per block; 4 waves in 2x2; 4x4 16x16x32 bf16 MFMA per wave.
// A/B tiles are contiguous 32KB global slabs (D==K==128): global_load_lds w/
// xor-swizzled source so LDS chunk c=(m,kq) holds global chunk (m, kq^(m&15)).
__global__ __launch_bounds__(256, 2) void gemm_kernel(
    const u16* __restrict__ A, const u16* __restrict__ B,
    const int* __restrict__ labels, float* __restrict__ partials)
{
    __shared__ u16 sA[128 * 128];
    __shared__ u16 sB[128 * 128];

    int tid  = threadIdx.x;
    int lane = tid & 63;
    int w    = tid >> 6;
    int wr   = w >> 1;
    int wc   = w & 1;
    int mrow = lane & 15;
    int q    = lane >> 4;

    int rowBase = blockIdx.y * 128;
    int colBase = blockIdx.x * 128;

    const u16* gA = A + (size_t)rowBase * DIM;
    const u16* gB = B + (size_t)colBase * DIM;

    // Stage both 32KB tiles: 8 iters x 256 threads x 16B each, xor-swizzled src.
    #pragma unroll
    for (int iter = 0; iter < 8; iter++) {
        int c  = iter * 256 + tid;          // destination chunk index (lane-ordered)
        int m  = c >> 4;
        int kq = (c & 15) ^ (m & 15);       // which global chunk lands here
        const u16* gpA = gA + (m * 16 + kq) * 8;
        const u16* gpB = gB + (m * 16 + kq) * 8;
        u16* lA = &sA[(size_t)c * 8 - (size_t)lane * 8];  // wave-uniform base
        u16* lB = &sB[(size_t)c * 8 - (size_t)lane * 8];
        __builtin_amdgcn_global_load_lds((const __attribute__((address_space(1))) void*)gpA,
                                         (__attribute__((address_space(3))) void*)lA, 16, 0, 0);
        __builtin_amdgcn_global_load_lds((const __attribute__((address_space(1))) void*)gpB,
                                         (__attribute__((address_space(3))) void*)lB, 16, 0, 0);
    }

    // Label preloads (independent of staging) — overlap with the LDS DMA.
    int iBase = rowBase + wr * 64 + q * 4;
    int jBase = colBase + wc * 64 + mrow;
    int li[16], lj[4];
    #pragma unroll
    for (int mi = 0; mi < 4; mi++)
        #pragma unroll
        for (int r = 0; r < 4; r++)
            li[mi * 4 + r] = labels[iBase + mi * 16 + r];
    #pragma unroll
    for (int ni = 0; ni < 4; ni++)
        lj[ni] = labels[jBase + ni * 16];

    f32x4 acc[4][4];
    #pragma unroll
    for (int mi = 0; mi < 4; mi++)
        #pragma unroll
        for (int ni = 0; ni < 4; ni++)
            acc[mi][ni] = (f32x4){0.f, 0.f, 0.f, 0.f};

    __syncthreads();

    #pragma unroll
    for (int ks = 0; ks < 4; ks++) {
        bf16x8 aF[4], bF[4];
        int kq = ks * 4 + q;
        #pragma unroll
        for (int mi = 0; mi < 4; mi++) {
            int m  = wr * 64 + mi * 16 + mrow;
            int ca = m * 16 + (kq ^ (m & 15));
            aF[mi] = *(const bf16x8*)&sA[ca * 8];
            int n  = wc * 64 + mi * 16 + mrow;
            int cb = n * 16 + (kq ^ (n & 15));
            bF[mi] = *(const bf16x8*)&sB[cb * 8];
        }
        #pragma unroll
        for (int mi = 0; mi < 4; mi++)
            #pragma unroll
            for (int ni = 0; ni < 4; ni++)
                acc[mi][ni] = __builtin_amdgcn_mfma_f32_16x16x32_bf16(
                    aF[mi], bF[ni], acc[mi][ni], 0, 0, 0);
    }

    // Epilogue: exp(-2*sim) masked by label inequality, thread-local sum.
    // exp(-2x) = exp2(x * (-2*log2(e)))
    const float CEXP = -2.0f * 1.44269504088896340736f;
    float s = 0.0f;
    #pragma unroll
    for (int mi = 0; mi < 4; mi++)
        #pragma unroll
        for (int ni = 0; ni < 4; ni++)
            #pragma unroll
            for (int r = 0; r < 4; r++) {
                float e = exp2f(acc[mi][ni][r] * CEXP);
                s += (li[mi * 4 + r] != lj[ni]) ? e : 0.0f;
            }

    #pragma unroll
    for (int off = 32; off; off >>= 1) s += __shfl_xor(s, off, 64);

    __syncthreads();                       // done with sA — reuse for reduction
    float* red = (float*)sA;
    if (lane == 0) red[w] = s;
    __syncthreads();
    if (tid == 0) {
        constexpr float SCALE = (float)(1.0 / (16384.0 * 16383.0));
        float t = (red[0] + red[1]) + (red[2] + red[3]);
        partials[blockIdx.y * 128 + blockIdx.x] = t * SCALE;
    }
}

__global__ __launch_bounds__(256) void reduce_kernel(
    const float* __restrict__ partials, float* __restrict__ out)
{
    int tid = threadIdx.x;
    float s = 0.0f;
    for (int i = tid; i < 16384; i += 256) s += partials[i];
    #pragma unroll
    for (int off = 32; off; off >>= 1) s += __shfl_xor(s, off, 64);
    __shared__ float red[4];
    if ((tid & 63) == 0) red[tid >> 6] = s;
    __syncthreads();
    if (tid == 0) out[0] = (red[0] + red[1]) + (red[2] + red[3]);
}

extern "C" void kernel_launch(void* const* d_in, const int* in_sizes, int n_in,
                              void* d_out, int out_size, void* d_ws, size_t ws_size,
                              hipStream_t stream) {
    const float* self_p = (const float*)d_in[0];
    const float* pos_p  = (const float*)d_in[1];
    const int*   labels = (const int*)d_in[2];
    float* out = (float*)d_out;

    u16* aB = (u16*)d_ws;                       // 4 MB bf16 normalized self
    u16* bB = aB + (size_t)NROWS * DIM;         // 4 MB bf16 normalized pos
    float* partials = (float*)(bB + (size_t)NROWS * DIM);  // 64 KB

    norm_kernel<<<NROWS / 4, 256, 0, stream>>>(self_p, pos_p, aB, bB);
    gemm_kernel<<<dim3(128, 128), 256, 0, stream>>>(aB, bB, labels, partials);
    reduce_kernel<<<1, 256, 0, stream>>>(partials, out);
}

// Round 2
// 183.138 us; speedup vs baseline: 1.1505x; 1.1505x over previous
//
#include <hip/hip_runtime.h>

typedef unsigned short u16;
typedef short bf16x8 __attribute__((ext_vector_type(8)));
typedef float f32x4 __attribute__((ext_vector_type(4)));

#define NROWS 16384
#define DIM 128

// exp(-2*sim) = exp2(sim * -2*log2(e)); scale folded into normalized B rows.
#define NEG2LOG2E -2.8853900817779268f

// round-to-nearest-even f32 -> bf16 (inputs are finite)
__device__ __forceinline__ u16 f2bf(float f) {
    unsigned int u = __float_as_uint(f);
    u += 0x7fffu + ((u >> 16) & 1u);
    return (u16)(u >> 16);
}

// One wave per row: L2-normalize rows of a and b, emit bf16.
// B rows additionally pre-scaled by -2*log2(e) so GEMM output feeds exp2 directly.
__global__ __launch_bounds__(256) void norm_kernel(
    const float* __restrict__ a, const float* __restrict__ b,
    u16* __restrict__ aO, u16* __restrict__ bO)
{
    int tid  = threadIdx.x;
    int lane = tid & 63;
    int w    = tid >> 6;
    long row = (long)blockIdx.x * 4 + w;

    const float2 va = ((const float2*)(a + row * DIM))[lane];
    float sa = va.x * va.x + va.y * va.y;
    #pragma unroll
    for (int off = 32; off; off >>= 1) sa += __shfl_xor(sa, off, 64);
    float inva = 1.0f / fmaxf(sqrtf(sa), 1e-12f);
    unsigned int pa = (unsigned int)f2bf(va.x * inva) | ((unsigned int)f2bf(va.y * inva) << 16);
    ((unsigned int*)(aO + row * DIM))[lane] = pa;

    const float2 vb = ((const float2*)(b + row * DIM))[lane];
    float sb = vb.x * vb.x + vb.y * vb.y;
    #pragma unroll
    for (int off = 32; off; off >>= 1) sb += __shfl_xor(sb, off, 64);
    float invb = NEG2LOG2E / fmaxf(sqrtf(sb), 1e-12f);
    unsigned int pb = (unsigned int)f2bf(vb.x * invb) | ((unsigned int)f2bf(vb.y * invb) << 16);
    ((unsigned int*)(bO + row * DIM))[lane] = pb;
}

// 128x128 C-tile per block; 4 waves in 2x2; 4x4 16x16x32 bf16 MFMA per wave.
// A/B tiles are contiguous 32KB global slabs (D==K==128): global_load_lds w/
// xor-swizzled source so LDS chunk c=(m,kq) holds global chunk (m, kq^(m&15)).
// Fragment LDS byte address: m<<8 | ((q ^ (m&15) ^ 4*ks)<<4) — disjoint bit
// fields, so per-ks address = base ^ (ks<<6): one v_xor per fragment.
__global__ __launch_bounds__(256, 2) void gemm_kernel(
    const u16* __restrict__ A, const u16* __restrict__ B,
    const int* __restrict__ labels, float* __restrict__ partials)
{
    __shared__ u16 sA[128 * 128];
    __shared__ u16 sB[128 * 128];

    int tid  = threadIdx.x;
    int lane = tid & 63;
    int w    = tid >> 6;
    int wr   = w >> 1;
    int wc   = w & 1;
    int mrow = lane & 15;
    int q    = lane >> 4;

    int rowBase = blockIdx.y * 128;
    int colBase = blockIdx.x * 128;

    const u16* gA = A + (size_t)rowBase * DIM;
    const u16* gB = B + (size_t)colBase * DIM;

    // Stage both 32KB tiles: 8 iters x 256 threads x 16B each, xor-swizzled src.
    #pragma unroll
    for (int iter = 0; iter < 8; iter++) {
        int c  = iter * 256 + tid;          // destination chunk index (lane-ordered)
        int m  = c >> 4;
        int kq = (c & 15) ^ (m & 15);       // which global chunk lands here
        const u16* gpA = gA + (m * 16 + kq) * 8;
        const u16* gpB = gB + (m * 16 + kq) * 8;
        u16* lA = &sA[(size_t)c * 8 - (size_t)lane * 8];  // wave-uniform base
        u16* lB = &sB[(size_t)c * 8 - (size_t)lane * 8];
        __builtin_amdgcn_global_load_lds((const __attribute__((address_space(1))) void*)gpA,
                                         (__attribute__((address_space(3))) void*)lA, 16, 0, 0);
        __builtin_amdgcn_global_load_lds((const __attribute__((address_space(1))) void*)gpB,
                                         (__attribute__((address_space(3))) void*)lB, 16, 0, 0);
    }

    // Label preloads (independent of staging) — overlap with the LDS DMA.
    int iBase = rowBase + wr * 64 + q * 4;
    int jBase = colBase + wc * 64 + mrow;
    int li[16], lj[4];
    #pragma unroll
    for (int mi = 0; mi < 4; mi++)
        #pragma unroll
        for (int r = 0; r < 4; r++)
            li[mi * 4 + r] = labels[iBase + mi * 16 + r];
    #pragma unroll
    for (int ni = 0; ni < 4; ni++)
        lj[ni] = labels[jBase + ni * 16];

    // Precompute fragment LDS byte offsets (ks=0); per-ks is base ^ (ks<<6).
    int aOff[4], bOff[4];
    #pragma unroll
    for (int mi = 0; mi < 4; mi++) {
        int m = wr * 64 + mi * 16 + mrow;
        aOff[mi] = (m << 8) | ((q ^ (m & 15)) << 4);
        int n = wc * 64 + mi * 16 + mrow;
        bOff[mi] = (n << 8) | ((q ^ (n & 15)) << 4);
    }

    f32x4 acc[4][4];
    #pragma unroll
    for (int mi = 0; mi < 4; mi++)
        #pragma unroll
        for (int ni = 0; ni < 4; ni++)
            acc[mi][ni] = (f32x4){0.f, 0.f, 0.f, 0.f};

    __syncthreads();

    const char* sAb = (const char*)sA;
    const char* sBb = (const char*)sB;
    #pragma unroll
    for (int ks = 0; ks < 4; ks++) {
        bf16x8 aF[4], bF[4];
        int x = ks << 6;
        #pragma unroll
        for (int mi = 0; mi < 4; mi++) {
            aF[mi] = *(const bf16x8*)(sAb + (aOff[mi] ^ x));
            bF[mi] = *(const bf16x8*)(sBb + (bOff[mi] ^ x));
        }
        #pragma unroll
        for (int mi = 0; mi < 4; mi++)
            #pragma unroll
            for (int ni = 0; ni < 4; ni++)
                acc[mi][ni] = __builtin_amdgcn_mfma_f32_16x16x32_bf16(
                    aF[mi], bF[ni], acc[mi][ni], 0, 0, 0);
    }

    // Epilogue: acc already = -2*log2e*sim; exp2 + label mask + local sum.
    float s0 = 0.0f, s1 = 0.0f;
    #pragma unroll
    for (int mi = 0; mi < 4; mi++)
        #pragma unroll
        for (int ni = 0; ni < 4; ni++)
            #pragma unroll
            for (int r = 0; r < 4; r++) {
                float e = __builtin_amdgcn_exp2f(acc[mi][ni][r]);
                float m = (li[mi * 4 + r] != lj[ni]) ? e : 0.0f;
                if (r & 1) s1 += m; else s0 += m;
            }
    float s = s0 + s1;

    #pragma unroll
    for (int off = 32; off; off >>= 1) s += __shfl_xor(s, off, 64);

    __syncthreads();                       // done with sA — reuse for reduction
    float* red = (float*)sA;
    if (lane == 0) red[w] = s;
    __syncthreads();
    if (tid == 0) {
        constexpr float SCALE = (float)(1.0 / (16384.0 * 16383.0));
        float t = (red[0] + red[1]) + (red[2] + red[3]);
        partials[blockIdx.y * 128 + blockIdx.x] = t * SCALE;
    }
}

__global__ __launch_bounds__(256) void reduce_kernel(
    const float* __restrict__ partials, float* __restrict__ out)
{
    int tid = threadIdx.x;
    float s = 0.0f;
    for (int i = tid; i < 16384; i += 256) s += partials[i];
    #pragma unroll
    for (int off = 32; off; off >>= 1) s += __shfl_xor(s, off, 64);
    __shared__ float red[4];
    if ((tid & 63) == 0) red[tid >> 6] = s;
    __syncthreads();
    if (tid == 0) out[0] = (red[0] + red[1]) + (red[2] + red[3]);
}

extern "C" void kernel_launch(void* const* d_in, const int* in_sizes, int n_in,
                              void* d_out, int out_size, void* d_ws, size_t ws_size,
                              hipStream_t stream) {
    const float* self_p = (const float*)d_in[0];
    const float* pos_p  = (const float*)d_in[1];
    const int*   labels = (const int*)d_in[2];
    float* out = (float*)d_out;

    u16* aB = (u16*)d_ws;                       // 4 MB bf16 normalized self
    u16* bB = aB + (size_t)NROWS * DIM;         // 4 MB bf16 normalized pos (pre-scaled)
    float* partials = (float*)(bB + (size_t)NROWS * DIM);  // 64 KB

    norm_kernel<<<NROWS / 4, 256, 0, stream>>>(self_p, pos_p, aB, bB);
    gemm_kernel<<<dim3(128, 128), 256, 0, stream>>>(aB, bB, labels, partials);
    reduce_kernel<<<1, 256, 0, stream>>>(partials, out);
}